// Round 13
// baseline (181.226 us; speedup 1.0000x reference)
//
#include <hip/hip_runtime.h>
#include <hip/hip_bf16.h>

typedef __attribute__((ext_vector_type(8))) short sh8;     // 8 bf16 (4 VGPRs)
typedef __attribute__((ext_vector_type(4))) float f32x4;   // MFMA C/D

#define LDC 136   // gemm epilogue C-tile stride in shorts
#define QSCALE 0.18033688f   // 0.125 * log2(e): folded into q at GEMM epilogue
#define KMBF16 0xF14Au       // bf16(-1e30): exp2(score-1e30) == 0 exactly

#define EXP2F(x) __builtin_amdgcn_exp2f(x)   // v_exp_f32 (base-2), no libm wrapper

// async global->LDS DMA, 16B/lane; LDS dest = wave-uniform base + lane*16 (m104/m108)
__device__ __forceinline__ void glds16(const unsigned short* g, unsigned short* l){
  __builtin_amdgcn_global_load_lds(
      (const __attribute__((address_space(1))) unsigned int*)g,
      (__attribute__((address_space(3))) unsigned int*)l, 16, 0, 0);
}

__device__ __forceinline__ unsigned short f2bf(float f){
  union { float f; unsigned u; } c; c.f = f;
  unsigned u = c.u;
  u += 0x7fffu + ((u >> 16) & 1u);   // RNE
  return (unsigned short)(u >> 16);
}

__device__ __forceinline__ unsigned long long pack4bf(float a, float b, float c, float d){
  __hip_bfloat162 lo = __float22bfloat162_rn(make_float2(a, b));  // v_cvt_pk_bf16_f32
  __hip_bfloat162 hi = __float22bfloat162_rn(make_float2(c, d));
  union { unsigned u[2]; unsigned long long ull; } pk;
  pk.u[0] = *(unsigned*)&lo; pk.u[1] = *(unsigned*)&hi;
  return pk.ull;
}

// ---------------- fp32 -> bf16 elementwise (x and Wo fused in one launch) ----------------
__global__ __launch_bounds__(256) void cvt_bf16_2(const float* __restrict__ s0,
                                                  unsigned short* __restrict__ d0, int n0,
                                                  const float* __restrict__ s1,
                                                  unsigned short* __restrict__ d1, int n1){
  int i = blockIdx.x*256 + threadIdx.x;
  const float* s; unsigned short* d;
  if (i < n0){ s = s0; d = d0; }
  else if (i < n0 + n1){ s = s1; d = d1; i -= n0; }
  else return;
  float4 v = ((const float4*)s)[i];
  ushort4 o;
  o.x = f2bf(v.x); o.y = f2bf(v.y); o.z = f2bf(v.z); o.w = f2bf(v.w);
  ((ushort4*)d)[i] = o;
}

// ---------------- Wq/Wk/Wv (H,D,DH) -> Wt[j=jm*1024+h*64+e][d] bf16 (B^T layout) ----------------
__global__ __launch_bounds__(256) void transpose_w(const float* __restrict__ Wq,
                                                   const float* __restrict__ Wk,
                                                   const float* __restrict__ Wv,
                                                   unsigned short* __restrict__ wt){
  __shared__ float tile[64][65];
  int idx = blockIdx.x;            // 0..767 = 3 * 16(h) * 16(dt)
  int jm = idx >> 8;
  int rest = idx & 255;
  int h = rest >> 4, dt = rest & 15;
  const float* src = (jm==0 ? Wq : (jm==1 ? Wk : Wv)) + (size_t)h*65536;  // [D][64] slab
  int t = threadIdx.x;
  {
    int r = t >> 2, c0 = (t & 3)*16;
    for (int i=0;i<4;++i){
      float4 v = *(const float4*)&src[(size_t)(dt*64 + r)*64 + c0 + i*4];
      tile[r][c0+i*4+0]=v.x; tile[r][c0+i*4+1]=v.y; tile[r][c0+i*4+2]=v.z; tile[r][c0+i*4+3]=v.w;
    }
  }
  __syncthreads();
  {
    int e = t >> 2, r0 = (t & 3)*16;
    int j = jm*1024 + h*64 + e;
    __align__(16) unsigned short buf[16];
    for (int i=0;i<16;++i) buf[i] = f2bf(tile[r0+i][e]);
    *(uint4*)&wt[(size_t)j*1024 + dt*64 + r0    ] = *(uint4*)&buf[0];
    *(uint4*)&wt[(size_t)j*1024 + dt*64 + r0 + 8] = *(uint4*)&buf[8];
  }
}

// ---------------- mask compaction scan: pidx[s] = stable prefix position (or -1) ----------------
// R11: prefetch all 32 dwords per lane first, then register-only ballot-prefix (~1us).
// Padding via hipMemsetAsync of kb/vtb (gemm0 writes only valid positions).
__global__ __launch_bounds__(64) void mask_scan(const int* __restrict__ mask,
                                                int* __restrict__ pidx){
  int b = blockIdx.x, lane = threadIdx.x;
  int m[32];
  #pragma unroll
  for (int c = 0; c < 32; ++c) m[c] = mask[b*2048 + c*64 + lane];   // independent loads
  int base = 0;
  #pragma unroll
  for (int c = 0; c < 32; ++c){
    unsigned long long bal = __ballot(m[c] != 0);
    int pos = base + (int)__popcll(bal & ((1ULL << lane) - 1ULL));
    pidx[b*2048 + c*64 + lane] = m[c] ? pos : -1;
    base += (int)__popcll(bal);
  }
}

// ---------------- GEMM C[M,N] = A[M,K] * Bt[N,K]^T, bf16 in / fp32 acc ----------------
// R13: BK=64 PROVEN swizzle (R12's BK=32 swizzle caused 3.48M bank conflicts; the BK=64
// pattern maps each 8-lane group onto all 32 banks exactly once -- measured 335K) +
// counted-vmcnt deep pipeline with 2 buffers. Per step:
//   wait vmcnt(LOADS) [next tile stays in flight] -> s_barrier -> ds_read ALL frags
//   -> lgkmcnt(0) -> s_barrier (LDS-only, cheap) -> stage(ks+2) into cb -> MFMAs.
// The read/stage split is what allows 2 buffers at depth 2: tile ks+2 overwrites cb
// only after every wave finished reading it; its DMA gets ~2 K-steps to land (R8's
// __syncthreads drained vmcnt(0) every step -> 60% stall).
// Same-XCD group swizzle kept. mode 0: fused QKV (k/v compacted via pidx). mode 2: Cf.
template<int BM>
__global__ __launch_bounds__(256) void gemm_bt(const unsigned short* __restrict__ A,
                                               const unsigned short* __restrict__ Bt,
                                               unsigned short* __restrict__ Cq,
                                               unsigned short* __restrict__ Ck,
                                               unsigned short* __restrict__ Cv,
                                               float* __restrict__ Cf,
                                               const int* __restrict__ pidx,
                                               int M, int N, int K, int mode){
  constexpr int MI = BM/32;                 // acc rows per wave (4 or 2)
  constexpr int ABUF = BM*64;               // shorts per A buffer (BK=64)
  constexpr int BBUF = 128*64;              // shorts per B buffer
  constexpr int BUFN = ABUF + BBUF;
  constexpr int TOTN = 2*BUFN;
  constexpr int SMEMN = (TOTN > 17664) ? TOTN : 17664;  // >= Ct(17408)+pS(128 ints)
  __shared__ __align__(16) unsigned short smem[SMEMN];
  const int t = threadIdx.x;
  const int w = t >> 6, lane = t & 63, l15 = lane & 15, quad = lane >> 4;

  // block swizzle: 8 m-blocks share one B-column tile AND one XCD
  int lin = blockIdx.y * gridDim.x + blockIdx.x;
  int gn = gridDim.x;
  int per = 8 * gn;
  int gid = lin / per, rem = lin % per;
  int j = rem / gn, nc = rem % gn;
  const int m0 = (gid*8 + j) * BM;
  const int n0 = nc * 128;

  const int wm = (w >> 1)*(BM/2), wn = (w & 1)*64;
  const int lr8 = lane >> 3;              // row within the wave's 8-row staging group
  const int gc8 = (lane & 7) ^ lr8;       // swizzled global chunk this lane fetches
  const int h7 = l15 & 7;
  f32x4 acc[MI][4] = {};

  // stage one BK=64 K-slice starting at k0 into buffer bb (async, no wait)
  auto stage = [&](int k0, int bb){
    unsigned short* as = smem + bb*BUFN;
    unsigned short* bs = as + ABUF;
    for (int p = 0; p < BM/32; ++p){
      int rbase = p*32 + w*8;             // wave-uniform
      glds16(&A [(size_t)(m0 + rbase + lr8)*K + k0 + gc8*8], &as[rbase*64]);
    }
    for (int p = 0; p < 4; ++p){
      int rbase = p*32 + w*8;
      glds16(&Bt[(size_t)(n0 + rbase + lr8)*K + k0 + gc8*8], &bs[rbase*64]);
    }
  };

  const int NS = K >> 6;                    // 16 steps at K=1024
  stage(0, 0);
  stage(64, 1);
  for (int ks = 0; ks < NS; ++ks){
    const int cb = ks & 1;
    // counted wait: tile ks's loads done, tile ks+1's stay in flight (T4)
    if (ks == NS - 1){
      asm volatile("s_waitcnt vmcnt(0)" ::: "memory");
    } else {
      if constexpr (BM == 128) asm volatile("s_waitcnt vmcnt(8)" ::: "memory");
      else                     asm volatile("s_waitcnt vmcnt(6)" ::: "memory");
    }
    __builtin_amdgcn_s_barrier();           // buffer cb complete for all waves
    __builtin_amdgcn_sched_barrier(0);

    const unsigned short* as = smem + cb*BUFN;
    const unsigned short* bs = as + ABUF;
    sh8 aF[2][MI], bF[2][4];
    #pragma unroll
    for (int kk = 0; kk < 2; ++kk){
      const int cs = (((kk<<2) + quad) ^ h7) * 8;
      for (int i = 0; i < MI; ++i)
        aF[kk][i] = *(const sh8*)&as[(wm + i*16 + l15)*64 + cs];
      for (int i = 0; i < 4; ++i)
        bF[kk][i] = *(const sh8*)&bs[(wn + i*16 + l15)*64 + cs];
    }
    asm volatile("s_waitcnt lgkmcnt(0)" ::: "memory");
    __builtin_amdgcn_sched_barrier(0);
    __builtin_amdgcn_s_barrier();           // all waves' reads of cb done
    __builtin_amdgcn_sched_barrier(0);
    if (ks + 2 < NS) stage((ks+2)*64, cb);  // overwrite cb; lands ~2 steps later

    #pragma unroll
    for (int kk = 0; kk < 2; ++kk)
      for (int mi = 0; mi < MI; ++mi)
        for (int ni = 0; ni < 4; ++ni)
          acc[mi][ni] = __builtin_amdgcn_mfma_f32_16x16x32_bf16(aF[kk][mi], bF[kk][ni], acc[mi][ni], 0, 0, 0);
  }

  // C/D layout: col = lane&15, row = quad*4 + r (m89/m91-verified)
  if (mode == 2){
    for (int mi = 0; mi < MI; ++mi){
      int rowb = m0 + wm + mi*16 + quad*4;
      for (int ni = 0; ni < 4; ++ni){
        int col = n0 + wn + ni*16 + l15;
        for (int r = 0; r < 4; ++r)
          Cf[(size_t)(rowb + r)*N + col] = acc[mi][ni][r];
      }
    }
    return;
  }

  if constexpr (BM == 128){
    // mode 0: LDS round-trip epilogue. Ct = 128x136 shorts aliases smem (bufs dead now).
    __syncthreads();
    unsigned short* Ct = smem;
    int* pS = (int*)(smem + 17408);       // pidx slice for this block's 128 s-rows
    const bool isv = (n0 >= 2048);
    const float cscale = (n0 < 1024) ? QSCALE : 1.0f;   // fold softmax scale into q
    const int b = m0 >> 11, sbase = m0 & 2047;
    for (int mi = 0; mi < 4; ++mi){
      for (int ni = 0; ni < 4; ++ni){
        for (int r = 0; r < 4; ++r){
          int lr = wm + mi*16 + quad*4 + r;   // local m (s) index
          int lc = wn + ni*16 + l15;          // local n (col) index
          unsigned short bv = f2bf(acc[mi][ni][r] * cscale);
          if (isv) Ct[lc*LDC + lr] = bv;      // transposed for V
          else     Ct[lr*LDC + lc] = bv;
        }
      }
    }
    if (t < 128) pS[t] = pidx[b*2048 + sbase + t];
    __syncthreads();

    const int hbase = (n0 & 1023) >> 6;
    if (!isv){
      const bool isq = (n0 < 1024);
      unsigned short* dst = isq ? Cq : Ck;
      for (int i = 0; i < 8; ++i){
        int s  = i*16 + (t >> 4);
        int hh = (t >> 3) & 1;
        int c  = t & 7;
        uint4 val = *(const uint4*)&Ct[s*LDC + hh*64 + c*8];
        int h = hbase + hh;
        int row;
        if (isq) row = sbase + s;
        else { int p = pS[s]; if (p < 0) continue; row = p; }   // compacted K row
        *(uint4*)&dst[((size_t)(b*16 + h)*2048 + row)*64 + c*8] = val;
      }
    } else {
      for (int i = 0; i < 8; ++i){
        int ecol = i*16 + (t >> 4);
        int s0   = (t & 15)*8;
        int hh = ecol >> 6, e = ecol & 63;
        int h = hbase + hh;
        unsigned short* dr = &Cv[((size_t)(b*16 + h)*64 + e)*2048];
        union { uint4 v; unsigned short us[8]; } val;
        val.v = *(const uint4*)&Ct[ecol*LDC + s0];   // vectorized LDS read
        #pragma unroll
        for (int jj = 0; jj < 8; ++jj){
          int p = pS[s0 + jj];
          if (p >= 0) dr[p] = val.us[jj];            // compacted V col (2B scatter)
        }
      }
    }
  }
}

// ---------------- flash attention over COMPACTED keys: 8 waves x 1 q-strip, dbuf ----------------
// R10/R11 verified: keys compacted to nv -> ntiles ~ 16-17 instead of 32 (flash < 46us).
// nv computed in-kernel from mask; pad-kill table (j<nv) kills the zero-padded tail;
// query mask applied at epilogue from mask[].
__global__ __launch_bounds__(512) void flash_attn(const unsigned short* __restrict__ q,
                                                  const unsigned short* __restrict__ k,
                                                  const unsigned short* __restrict__ vt,
                                                  const int* __restrict__ mask,
                                                  unsigned short* __restrict__ ctx){
  __shared__ __align__(16) unsigned short Ks[2][4096];   // [buf][64 key][64 e] xor-swizzled
  __shared__ __align__(16) unsigned short Vs[2][4096];   // [buf][64 e][64 key] xor-swizzled
  __shared__ __align__(16) unsigned short Ps[8][1024];   // [wave][16 qrow][64 key] xor-swz
  __shared__ __align__(16) unsigned short kmb[2048];     // bf16 adds: j<nv ? 0 : -1e30
  __shared__ int s_nv;

  const int idx = blockIdx.x;
  const int xcd = idx & 7, sub = idx >> 3;
  const int bh = xcd*4 + (sub & 3);           // 4 (b,h) per XCD -> K/V L2-resident
  const int qt = sub >> 2;                    // 0..15
  const int b = bh >> 4, h = bh & 15;
  const int t = threadIdx.x;
  const int w = t >> 6, lane = t & 63, l15 = lane & 15, quad = lane >> 4;
  const size_t base = (size_t)bh * 2048 * 64;

  // Q B-fragments for this wave's strip straight from global (q pre-scaled by QSCALE)
  const unsigned short* qp0 = q + base + (size_t)(qt*128 + w*16 + l15)*64;
  sh8 qf[2];
  qf[0] = *(const sh8*)(qp0 +      quad*8);
  qf[1] = *(const sh8*)(qp0 + 32 + quad*8);

  // count valid keys (nv) from mask: 512 threads x 4 ints, wave-reduce + one atomic/wave
  if (t == 0) s_nv = 0;
  int4 mv = ((const int4*)(mask + b*2048))[t];
  __syncthreads();
  {
    int c = (mv.x != 0) + (mv.y != 0) + (mv.z != 0) + (mv.w != 0);
    c += __shfl_down(c, 32); c += __shfl_down(c, 16); c += __shfl_down(c, 8);
    c += __shfl_down(c, 4);  c += __shfl_down(c, 2);  c += __shfl_down(c, 1);
    if (lane == 0) atomicAdd(&s_nv, c);
  }
  __syncthreads();
  const int nv = s_nv;
  const int ntiles = (nv + 63) >> 6;

  { // build pad-kill table: entry j = (j < nv) ? 0 : bf16(-1e30)
    __align__(8) unsigned short tmp[4];
    #pragma unroll
    for (int i = 0; i < 4; ++i) tmp[i] = (t*4 + i < nv) ? 0 : (unsigned short)KMBF16;
    *(unsigned long long*)&kmb[t*4] = *(unsigned long long*)tmp;
  }

  const int lr8 = lane >> 3;              // staging row within 8-row group
  const int gc8 = (lane & 7) ^ lr8;       // swizzled global source chunk
  const int h7 = l15 & 7;
  const int cs0 = ((quad    ) ^ h7) * 8;  // kk=0 swizzled read chunk (K/V tiles)
  const int cs1 = ((quad + 4) ^ h7) * 8;  // kk=1
  // Ps swizzle: write chunk8 (mt*2+(quad>>1))^h7 (+ (quad&1)*4), read chunk8 (kk*4+quad)^h7
  const int pw_off = (quad & 1)*4;
  const int pr0 = ((0*4 + quad) ^ h7) * 8;
  const int pr1 = ((1*4 + quad) ^ h7) * 8;

  // stage compacted K/V tile kt into buffer bb: wave w covers rows w*8..w*8+7 (1 glds each)
  auto stageKV = [&](int kt, int bb){
    int r0 = w*8;                         // wave-uniform LDS base row
    glds16(&k [base + (size_t)(kt*64 + r0 + lr8)*64 + gc8*8], &Ks[bb][r0*64]);
    glds16(&vt[base + (size_t)(r0 + lr8)*2048 + kt*64 + gc8*8], &Vs[bb][r0*64]);
  };

  float la[4] = {};
  f32x4 O[4] = {};   // O^T[et]: row=quad*4+r=e, col=l15=qrow

  if (ntiles > 0) stageKV(0, 0);
  for (int kt = 0; kt < ntiles; ++kt){
    const int bb = kt & 1;
    __syncthreads();                      // buf bb staged; prev compute done
    if (kt + 1 < ntiles) stageKV(kt + 1, bb ^ 1);   // async into other buffer

    // S^T = K·Q^T + km (pad-kill folded into the MFMA C-init)
    for (int mt = 0; mt < 4; ++mt){
      sh8 a0 = *(const sh8*)&Ks[bb][(mt*16 + l15)*64 + cs0];
      sh8 a1 = *(const sh8*)&Ks[bb][(mt*16 + l15)*64 + cs1];
      unsigned long long kq = *(const unsigned long long*)&kmb[kt*64 + mt*16 + quad*4];
      unsigned d0 = (unsigned)kq, d1 = (unsigned)(kq >> 32);
      f32x4 a;
      a[0] = __uint_as_float(d0 << 16);
      a[1] = __uint_as_float(d0 & 0xFFFF0000u);
      a[2] = __uint_as_float(d1 << 16);
      a[3] = __uint_as_float(d1 & 0xFFFF0000u);
      const int pwc = (((mt*2 + (quad>>1)) ^ h7) * 8) + pw_off;
      a = __builtin_amdgcn_mfma_f32_16x16x32_bf16(a0, qf[0], a, 0, 0, 0);
      a = __builtin_amdgcn_mfma_f32_16x16x32_bf16(a1, qf[1], a, 0, 0, 0);
      float e0 = EXP2F(a[0]); la[0] += e0;
      float e1 = EXP2F(a[1]); la[1] += e1;
      float e2 = EXP2F(a[2]); la[2] += e2;
      float e3 = EXP2F(a[3]); la[3] += e3;
      *(unsigned long long*)&Ps[w][l15*64 + pwc] = pack4bf(e0, e1, e2, e3);
    }

    // O^T += V^T · P (Ps per-wave: no barrier needed)
    sh8 pf0 = *(const sh8*)&Ps[w][l15*64 + pr0];
    sh8 pf1 = *(const sh8*)&Ps[w][l15*64 + pr1];
    for (int et = 0; et < 4; ++et){
      sh8 vf0 = *(const sh8*)&Vs[bb][(et*16 + l15)*64 + cs0];
      O[et] = __builtin_amdgcn_mfma_f32_16x16x32_bf16(vf0, pf0, O[et], 0, 0, 0);
    }
    for (int et = 0; et < 4; ++et){
      sh8 vf1 = *(const sh8*)&Vs[bb][(et*16 + l15)*64 + cs1];
      O[et] = __builtin_amdgcn_mfma_f32_16x16x32_bf16(vf1, pf1, O[et], 0, 0, 0);
    }
  }

  // epilogue: final l reduction, /l, query-mask zeroing (from original mask)
  {
    float l_i = (la[0] + la[1]) + (la[2] + la[3]);
    l_i += __shfl_xor(l_i, 16);
    l_i += __shfl_xor(l_i, 32);
    int srow = qt*128 + w*16 + l15;
    bool qm = (mask[b*2048 + srow] != 0);
    float inv = (qm && l_i > 0.f) ? 1.f/l_i : 0.f;
    unsigned short* crow = ctx + (((size_t)b*2048 + srow)*16 + h)*64;
    for (int et = 0; et < 4; ++et)
      *(unsigned long long*)&crow[et*16 + quad*4] =
        pack4bf(O[et][0]*inv, O[et][1]*inv, O[et][2]*inv, O[et][3]*inv);
  }
}

extern "C" void kernel_launch(void* const* d_in, const int* in_sizes, int n_in,
                              void* d_out, int out_size, void* d_ws, size_t ws_size,
                              hipStream_t stream){
  const float* x  = (const float*)d_in[0];
  const int* mask = (const int*)  d_in[1];
  const float* Wq = (const float*)d_in[2];
  const float* Wk = (const float*)d_in[3];
  const float* Wv = (const float*)d_in[4];
  const float* Wo = (const float*)d_in[5];
  float* out = (float*)d_out;

  char* ws = (char*)d_ws;                                  // total 48 MiB
  unsigned short* x_bf  = (unsigned short*)(ws);           //  8 MiB  [4096][1024]
  unsigned short* wt    = (unsigned short*)(ws + 8388608); //  6 MiB  [3072][1024] (QKV B^T)
  unsigned short* wo_bf = (unsigned short*)(ws + 14680064);//  2 MiB  [1024][1024]
  unsigned short* qb    = (unsigned short*)(ws + 16777216);//  8 MiB  [b][h][s][e] (pre-scaled)
  unsigned short* kb    = (unsigned short*)(ws + 25165824);//  8 MiB  compacted [b][h][j][e]
  unsigned short* vtb   = (unsigned short*)(ws + 33554432);//  8 MiB  compacted [b][h][e][j]
  unsigned short* ctx   = (unsigned short*)(ws + 41943040);//  8 MiB  [b][s][h*64+e]
  // pidx lives scan->gemm0 only; ctx region is dead until flash -> alias is safe
  int*            pidx  = (int*)(ws + 41943040);           // 16 KB   [b][s] compacted pos

  hipMemsetAsync(ws + 25165824, 0, 16777216, stream);      // zero kb+vtb (pad stays 0)
  mask_scan<<<2, 64, 0, stream>>>(mask, pidx);
  cvt_bf16_2<<<5120, 256, 0, stream>>>(x, x_bf, 1048576, Wo, wo_bf, 262144);
  transpose_w<<<768, 256, 0, stream>>>(Wq, Wk, Wv, wt);
  gemm_bt<128><<<dim3(24, 32), 256, 0, stream>>>(x_bf, wt, qb, kb, vtb, nullptr, pidx, 4096, 3072, 1024, 0);
  flash_attn<<<512, 512, 0, stream>>>(qb, kb, vtb, mask, ctx);
  gemm_bt<64><<<dim3(8, 64), 256, 0, stream>>>(ctx, wo_bf, nullptr, nullptr, nullptr, out, pidx, 4096, 1024, 1024, 2);
}

// Round 14
// 172.722 us; speedup vs baseline: 1.0492x; 1.0492x over previous
//
#include <hip/hip_runtime.h>
#include <hip/hip_bf16.h>

typedef __attribute__((ext_vector_type(8))) short sh8;     // 8 bf16 (4 VGPRs)
typedef __attribute__((ext_vector_type(4))) float f32x4;   // MFMA C/D

#define LDC 136   // gemm epilogue C-tile stride in shorts
#define QSCALE 0.18033688f   // 0.125 * log2(e): folded into q at GEMM epilogue
#define KMBF16 0xF14Au       // bf16(-1e30): exp2(score-1e30) == 0 exactly

#define EXP2F(x) __builtin_amdgcn_exp2f(x)   // v_exp_f32 (base-2), no libm wrapper

// async global->LDS DMA, 16B/lane; LDS dest = wave-uniform base + lane*16 (m104/m108)
__device__ __forceinline__ void glds16(const unsigned short* g, unsigned short* l){
  __builtin_amdgcn_global_load_lds(
      (const __attribute__((address_space(1))) unsigned int*)g,
      (__attribute__((address_space(3))) unsigned int*)l, 16, 0, 0);
}

__device__ __forceinline__ unsigned short f2bf(float f){
  union { float f; unsigned u; } c; c.f = f;
  unsigned u = c.u;
  u += 0x7fffu + ((u >> 16) & 1u);   // RNE
  return (unsigned short)(u >> 16);
}

__device__ __forceinline__ unsigned long long pack4bf(float a, float b, float c, float d){
  __hip_bfloat162 lo = __float22bfloat162_rn(make_float2(a, b));  // v_cvt_pk_bf16_f32
  __hip_bfloat162 hi = __float22bfloat162_rn(make_float2(c, d));
  union { unsigned u[2]; unsigned long long ull; } pk;
  pk.u[0] = *(unsigned*)&lo; pk.u[1] = *(unsigned*)&hi;
  return pk.ull;
}

// ---------------- fused prep: zero kb/vtb + mask scan + fp32->bf16 cvt + W transpose ----------------
// R14: 7 dispatches -> 4. Kernel sum was ~115us vs dur 181 => ~65us of inter-dispatch
// overhead (~9us each). These four steps are mutually independent -> one kernel,
// partitioned by blockIdx: [0,4096) zero 16MiB kb+vtb; [4096,9216) cvt x/Wo;
// [9216,9984) transpose Wq/Wk/Wv; [9984,9986) mask scan. All overlap on-chip.
#define PREP_ZB   4096
#define PREP_CVT  5120
#define PREP_TR   768
__global__ __launch_bounds__(256) void prep(const float* __restrict__ x,
                                            const float* __restrict__ Wo,
                                            const float* __restrict__ Wq,
                                            const float* __restrict__ Wk,
                                            const float* __restrict__ Wv,
                                            const int* __restrict__ mask,
                                            unsigned short* __restrict__ x_bf,
                                            unsigned short* __restrict__ wo_bf,
                                            unsigned short* __restrict__ wt,
                                            unsigned short* __restrict__ kb_zero,  // kb base (16MiB contiguous with vtb)
                                            int* __restrict__ pidx){
  __shared__ float tile[64][65];
  const int blk = blockIdx.x;
  const int t = threadIdx.x;

  if (blk < PREP_ZB){
    // zero kb+vtb (16 MiB): pads stay 0; gemm0 writes only valid positions
    ((uint4*)kb_zero)[(size_t)blk*256 + t] = make_uint4(0,0,0,0);
    return;
  }
  if (blk < PREP_ZB + PREP_CVT){
    int i = (blk - PREP_ZB)*256 + t;
    const float* s; unsigned short* d;
    if (i < 1048576){ s = x; d = x_bf; }
    else { s = Wo; d = wo_bf; i -= 1048576; }
    float4 v = ((const float4*)s)[i];
    ushort4 o;
    o.x = f2bf(v.x); o.y = f2bf(v.y); o.z = f2bf(v.z); o.w = f2bf(v.w);
    ((ushort4*)d)[i] = o;
    return;
  }
  if (blk < PREP_ZB + PREP_CVT + PREP_TR){
    int idx = blk - (PREP_ZB + PREP_CVT);    // 0..767 = 3 * 16(h) * 16(dt)
    int jm = idx >> 8;
    int rest = idx & 255;
    int h = rest >> 4, dt = rest & 15;
    const float* src = (jm==0 ? Wq : (jm==1 ? Wk : Wv)) + (size_t)h*65536;  // [D][64] slab
    {
      int r = t >> 2, c0 = (t & 3)*16;
      for (int i=0;i<4;++i){
        float4 v = *(const float4*)&src[(size_t)(dt*64 + r)*64 + c0 + i*4];
        tile[r][c0+i*4+0]=v.x; tile[r][c0+i*4+1]=v.y; tile[r][c0+i*4+2]=v.z; tile[r][c0+i*4+3]=v.w;
      }
    }
    __syncthreads();
    {
      int e = t >> 2, r0 = (t & 3)*16;
      int j = jm*1024 + h*64 + e;
      __align__(16) unsigned short buf[16];
      for (int i=0;i<16;++i) buf[i] = f2bf(tile[r0+i][e]);
      *(uint4*)&wt[(size_t)j*1024 + dt*64 + r0    ] = *(uint4*)&buf[0];
      *(uint4*)&wt[(size_t)j*1024 + dt*64 + r0 + 8] = *(uint4*)&buf[8];
    }
    return;
  }
  {
    // mask compaction scan (R11-verified): prefetch all 32 dwords, register ballot-prefix
    int b = blk - (PREP_ZB + PREP_CVT + PREP_TR);
    if (t >= 64) return;
    int lane = t;
    int m[32];
    #pragma unroll
    for (int c = 0; c < 32; ++c) m[c] = mask[b*2048 + c*64 + lane];   // independent loads
    int base = 0;
    #pragma unroll
    for (int c = 0; c < 32; ++c){
      unsigned long long bal = __ballot(m[c] != 0);
      int pos = base + (int)__popcll(bal & ((1ULL << lane) - 1ULL));
      pidx[b*2048 + c*64 + lane] = m[c] ? pos : -1;
      base += (int)__popcll(bal);
    }
  }
}

// ---------------- GEMM C[M,N] = A[M,K] * Bt[N,K]^T, bf16 in / fp32 acc ----------------
// R13: BK=64 proven swizzle + counted-vmcnt deep pipeline, 2 buffers. Per step:
//   wait vmcnt(LOADS) [next tile in flight] -> s_barrier -> ds_read ALL frags
//   -> lgkmcnt(0) -> s_barrier (LDS-only) -> stage(ks+2) into cb -> MFMAs.
// Same-XCD group swizzle. mode 0: fused QKV (k/v compacted via pidx). mode 2: Cf.
template<int BM>
__global__ __launch_bounds__(256) void gemm_bt(const unsigned short* __restrict__ A,
                                               const unsigned short* __restrict__ Bt,
                                               unsigned short* __restrict__ Cq,
                                               unsigned short* __restrict__ Ck,
                                               unsigned short* __restrict__ Cv,
                                               float* __restrict__ Cf,
                                               const int* __restrict__ pidx,
                                               int M, int N, int K, int mode){
  constexpr int MI = BM/32;                 // acc rows per wave (4 or 2)
  constexpr int ABUF = BM*64;               // shorts per A buffer (BK=64)
  constexpr int BBUF = 128*64;              // shorts per B buffer
  constexpr int BUFN = ABUF + BBUF;
  constexpr int TOTN = 2*BUFN;
  constexpr int SMEMN = (TOTN > 17664) ? TOTN : 17664;  // >= Ct(17408)+pS(128 ints)
  __shared__ __align__(16) unsigned short smem[SMEMN];
  const int t = threadIdx.x;
  const int w = t >> 6, lane = t & 63, l15 = lane & 15, quad = lane >> 4;

  // block swizzle: 8 m-blocks share one B-column tile AND one XCD
  int lin = blockIdx.y * gridDim.x + blockIdx.x;
  int gn = gridDim.x;
  int per = 8 * gn;
  int gid = lin / per, rem = lin % per;
  int j = rem / gn, nc = rem % gn;
  const int m0 = (gid*8 + j) * BM;
  const int n0 = nc * 128;

  const int wm = (w >> 1)*(BM/2), wn = (w & 1)*64;
  const int lr8 = lane >> 3;              // row within the wave's 8-row staging group
  const int gc8 = (lane & 7) ^ lr8;       // swizzled global chunk this lane fetches
  const int h7 = l15 & 7;
  f32x4 acc[MI][4] = {};

  // stage one BK=64 K-slice starting at k0 into buffer bb (async, no wait)
  auto stage = [&](int k0, int bb){
    unsigned short* as = smem + bb*BUFN;
    unsigned short* bs = as + ABUF;
    for (int p = 0; p < BM/32; ++p){
      int rbase = p*32 + w*8;             // wave-uniform
      glds16(&A [(size_t)(m0 + rbase + lr8)*K + k0 + gc8*8], &as[rbase*64]);
    }
    for (int p = 0; p < 4; ++p){
      int rbase = p*32 + w*8;
      glds16(&Bt[(size_t)(n0 + rbase + lr8)*K + k0 + gc8*8], &bs[rbase*64]);
    }
  };

  const int NS = K >> 6;                    // 16 steps at K=1024
  stage(0, 0);
  stage(64, 1);
  for (int ks = 0; ks < NS; ++ks){
    const int cb = ks & 1;
    // counted wait: tile ks's loads done, tile ks+1's stay in flight (T4)
    if (ks == NS - 1){
      asm volatile("s_waitcnt vmcnt(0)" ::: "memory");
    } else {
      if constexpr (BM == 128) asm volatile("s_waitcnt vmcnt(8)" ::: "memory");
      else                     asm volatile("s_waitcnt vmcnt(6)" ::: "memory");
    }
    __builtin_amdgcn_s_barrier();           // buffer cb complete for all waves
    __builtin_amdgcn_sched_barrier(0);

    const unsigned short* as = smem + cb*BUFN;
    const unsigned short* bs = as + ABUF;
    sh8 aF[2][MI], bF[2][4];
    #pragma unroll
    for (int kk = 0; kk < 2; ++kk){
      const int cs = (((kk<<2) + quad) ^ h7) * 8;
      for (int i = 0; i < MI; ++i)
        aF[kk][i] = *(const sh8*)&as[(wm + i*16 + l15)*64 + cs];
      for (int i = 0; i < 4; ++i)
        bF[kk][i] = *(const sh8*)&bs[(wn + i*16 + l15)*64 + cs];
    }
    asm volatile("s_waitcnt lgkmcnt(0)" ::: "memory");
    __builtin_amdgcn_sched_barrier(0);
    __builtin_amdgcn_s_barrier();           // all waves' reads of cb done
    __builtin_amdgcn_sched_barrier(0);
    if (ks + 2 < NS) stage((ks+2)*64, cb);  // overwrite cb; lands ~2 steps later

    #pragma unroll
    for (int kk = 0; kk < 2; ++kk)
      for (int mi = 0; mi < MI; ++mi)
        for (int ni = 0; ni < 4; ++ni)
          acc[mi][ni] = __builtin_amdgcn_mfma_f32_16x16x32_bf16(aF[kk][mi], bF[kk][ni], acc[mi][ni], 0, 0, 0);
  }

  // C/D layout: col = lane&15, row = quad*4 + r (m89/m91-verified)
  if (mode == 2){
    for (int mi = 0; mi < MI; ++mi){
      int rowb = m0 + wm + mi*16 + quad*4;
      for (int ni = 0; ni < 4; ++ni){
        int col = n0 + wn + ni*16 + l15;
        for (int r = 0; r < 4; ++r)
          Cf[(size_t)(rowb + r)*N + col] = acc[mi][ni][r];
      }
    }
    return;
  }

  if constexpr (BM == 128){
    // mode 0: LDS round-trip epilogue. Ct = 128x136 shorts aliases smem (bufs dead now).
    __syncthreads();
    unsigned short* Ct = smem;
    int* pS = (int*)(smem + 17408);       // pidx slice for this block's 128 s-rows
    const bool isv = (n0 >= 2048);
    const float cscale = (n0 < 1024) ? QSCALE : 1.0f;   // fold softmax scale into q
    const int b = m0 >> 11, sbase = m0 & 2047;
    for (int mi = 0; mi < 4; ++mi){
      for (int ni = 0; ni < 4; ++ni){
        for (int r = 0; r < 4; ++r){
          int lr = wm + mi*16 + quad*4 + r;   // local m (s) index
          int lc = wn + ni*16 + l15;          // local n (col) index
          unsigned short bv = f2bf(acc[mi][ni][r] * cscale);
          if (isv) Ct[lc*LDC + lr] = bv;      // transposed for V
          else     Ct[lr*LDC + lc] = bv;
        }
      }
    }
    if (t < 128) pS[t] = pidx[b*2048 + sbase + t];
    __syncthreads();

    const int hbase = (n0 & 1023) >> 6;
    if (!isv){
      const bool isq = (n0 < 1024);
      unsigned short* dst = isq ? Cq : Ck;
      for (int i = 0; i < 8; ++i){
        int s  = i*16 + (t >> 4);
        int hh = (t >> 3) & 1;
        int c  = t & 7;
        uint4 val = *(const uint4*)&Ct[s*LDC + hh*64 + c*8];
        int h = hbase + hh;
        int row;
        if (isq) row = sbase + s;
        else { int p = pS[s]; if (p < 0) continue; row = p; }   // compacted K row
        *(uint4*)&dst[((size_t)(b*16 + h)*2048 + row)*64 + c*8] = val;
      }
    } else {
      for (int i = 0; i < 8; ++i){
        int ecol = i*16 + (t >> 4);
        int s0   = (t & 15)*8;
        int hh = ecol >> 6, e = ecol & 63;
        int h = hbase + hh;
        unsigned short* dr = &Cv[((size_t)(b*16 + h)*64 + e)*2048];
        union { uint4 v; unsigned short us[8]; } val;
        val.v = *(const uint4*)&Ct[ecol*LDC + s0];   // vectorized LDS read
        #pragma unroll
        for (int jj = 0; jj < 8; ++jj){
          int p = pS[s0 + jj];
          if (p >= 0) dr[p] = val.us[jj];            // compacted V col (2B scatter)
        }
      }
    }
  }
}

// ---------------- flash attention over COMPACTED keys: 8 waves x 1 q-strip, dbuf ----------------
// R10/R11 verified: keys compacted to nv -> ntiles ~ 16-17 instead of 32 (flash < 46us).
// nv computed in-kernel from mask; pad-kill table (j<nv) kills the zero-padded tail;
// query mask applied at epilogue from mask[].
__global__ __launch_bounds__(512) void flash_attn(const unsigned short* __restrict__ q,
                                                  const unsigned short* __restrict__ k,
                                                  const unsigned short* __restrict__ vt,
                                                  const int* __restrict__ mask,
                                                  unsigned short* __restrict__ ctx){
  __shared__ __align__(16) unsigned short Ks[2][4096];   // [buf][64 key][64 e] xor-swizzled
  __shared__ __align__(16) unsigned short Vs[2][4096];   // [buf][64 e][64 key] xor-swizzled
  __shared__ __align__(16) unsigned short Ps[8][1024];   // [wave][16 qrow][64 key] xor-swz
  __shared__ __align__(16) unsigned short kmb[2048];     // bf16 adds: j<nv ? 0 : -1e30
  __shared__ int s_nv;

  const int idx = blockIdx.x;
  const int xcd = idx & 7, sub = idx >> 3;
  const int bh = xcd*4 + (sub & 3);           // 4 (b,h) per XCD -> K/V L2-resident
  const int qt = sub >> 2;                    // 0..15
  const int b = bh >> 4, h = bh & 15;
  const int t = threadIdx.x;
  const int w = t >> 6, lane = t & 63, l15 = lane & 15, quad = lane >> 4;
  const size_t base = (size_t)bh * 2048 * 64;

  // Q B-fragments for this wave's strip straight from global (q pre-scaled by QSCALE)
  const unsigned short* qp0 = q + base + (size_t)(qt*128 + w*16 + l15)*64;
  sh8 qf[2];
  qf[0] = *(const sh8*)(qp0 +      quad*8);
  qf[1] = *(const sh8*)(qp0 + 32 + quad*8);

  // count valid keys (nv) from mask: 512 threads x 4 ints, wave-reduce + one atomic/wave
  if (t == 0) s_nv = 0;
  int4 mv = ((const int4*)(mask + b*2048))[t];
  __syncthreads();
  {
    int c = (mv.x != 0) + (mv.y != 0) + (mv.z != 0) + (mv.w != 0);
    c += __shfl_down(c, 32); c += __shfl_down(c, 16); c += __shfl_down(c, 8);
    c += __shfl_down(c, 4);  c += __shfl_down(c, 2);  c += __shfl_down(c, 1);
    if (lane == 0) atomicAdd(&s_nv, c);
  }
  __syncthreads();
  const int nv = s_nv;
  const int ntiles = (nv + 63) >> 6;

  { // build pad-kill table: entry j = (j < nv) ? 0 : bf16(-1e30)
    __align__(8) unsigned short tmp[4];
    #pragma unroll
    for (int i = 0; i < 4; ++i) tmp[i] = (t*4 + i < nv) ? 0 : (unsigned short)KMBF16;
    *(unsigned long long*)&kmb[t*4] = *(unsigned long long*)tmp;
  }

  const int lr8 = lane >> 3;              // staging row within 8-row group
  const int gc8 = (lane & 7) ^ lr8;       // swizzled global source chunk
  const int h7 = l15 & 7;
  const int cs0 = ((quad    ) ^ h7) * 8;  // kk=0 swizzled read chunk (K/V tiles)
  const int cs1 = ((quad + 4) ^ h7) * 8;  // kk=1
  // Ps swizzle: write chunk8 (mt*2+(quad>>1))^h7 (+ (quad&1)*4), read chunk8 (kk*4+quad)^h7
  const int pw_off = (quad & 1)*4;
  const int pr0 = ((0*4 + quad) ^ h7) * 8;
  const int pr1 = ((1*4 + quad) ^ h7) * 8;

  // stage compacted K/V tile kt into buffer bb: wave w covers rows w*8..w*8+7 (1 glds each)
  auto stageKV = [&](int kt, int bb){
    int r0 = w*8;                         // wave-uniform LDS base row
    glds16(&k [base + (size_t)(kt*64 + r0 + lr8)*64 + gc8*8], &Ks[bb][r0*64]);
    glds16(&vt[base + (size_t)(r0 + lr8)*2048 + kt*64 + gc8*8], &Vs[bb][r0*64]);
  };

  float la[4] = {};
  f32x4 O[4] = {};   // O^T[et]: row=quad*4+r=e, col=l15=qrow

  if (ntiles > 0) stageKV(0, 0);
  for (int kt = 0; kt < ntiles; ++kt){
    const int bb = kt & 1;
    __syncthreads();                      // buf bb staged; prev compute done
    if (kt + 1 < ntiles) stageKV(kt + 1, bb ^ 1);   // async into other buffer

    // S^T = K·Q^T + km (pad-kill folded into the MFMA C-init)
    for (int mt = 0; mt < 4; ++mt){
      sh8 a0 = *(const sh8*)&Ks[bb][(mt*16 + l15)*64 + cs0];
      sh8 a1 = *(const sh8*)&Ks[bb][(mt*16 + l15)*64 + cs1];
      unsigned long long kq = *(const unsigned long long*)&kmb[kt*64 + mt*16 + quad*4];
      unsigned d0 = (unsigned)kq, d1 = (unsigned)(kq >> 32);
      f32x4 a;
      a[0] = __uint_as_float(d0 << 16);
      a[1] = __uint_as_float(d0 & 0xFFFF0000u);
      a[2] = __uint_as_float(d1 << 16);
      a[3] = __uint_as_float(d1 & 0xFFFF0000u);
      const int pwc = (((mt*2 + (quad>>1)) ^ h7) * 8) + pw_off;
      a = __builtin_amdgcn_mfma_f32_16x16x32_bf16(a0, qf[0], a, 0, 0, 0);
      a = __builtin_amdgcn_mfma_f32_16x16x32_bf16(a1, qf[1], a, 0, 0, 0);
      float e0 = EXP2F(a[0]); la[0] += e0;
      float e1 = EXP2F(a[1]); la[1] += e1;
      float e2 = EXP2F(a[2]); la[2] += e2;
      float e3 = EXP2F(a[3]); la[3] += e3;
      *(unsigned long long*)&Ps[w][l15*64 + pwc] = pack4bf(e0, e1, e2, e3);
    }

    // O^T += V^T · P (Ps per-wave: no barrier needed)
    sh8 pf0 = *(const sh8*)&Ps[w][l15*64 + pr0];
    sh8 pf1 = *(const sh8*)&Ps[w][l15*64 + pr1];
    for (int et = 0; et < 4; ++et){
      sh8 vf0 = *(const sh8*)&Vs[bb][(et*16 + l15)*64 + cs0];
      O[et] = __builtin_amdgcn_mfma_f32_16x16x32_bf16(vf0, pf0, O[et], 0, 0, 0);
    }
    for (int et = 0; et < 4; ++et){
      sh8 vf1 = *(const sh8*)&Vs[bb][(et*16 + l15)*64 + cs1];
      O[et] = __builtin_amdgcn_mfma_f32_16x16x32_bf16(vf1, pf1, O[et], 0, 0, 0);
    }
  }

  // epilogue: final l reduction, /l, query-mask zeroing (from original mask)
  {
    float l_i = (la[0] + la[1]) + (la[2] + la[3]);
    l_i += __shfl_xor(l_i, 16);
    l_i += __shfl_xor(l_i, 32);
    int srow = qt*128 + w*16 + l15;
    bool qm = (mask[b*2048 + srow] != 0);
    float inv = (qm && l_i > 0.f) ? 1.f/l_i : 0.f;
    unsigned short* crow = ctx + (((size_t)b*2048 + srow)*16 + h)*64;
    for (int et = 0; et < 4; ++et)
      *(unsigned long long*)&crow[et*16 + quad*4] =
        pack4bf(O[et][0]*inv, O[et][1]*inv, O[et][2]*inv, O[et][3]*inv);
  }
}

extern "C" void kernel_launch(void* const* d_in, const int* in_sizes, int n_in,
                              void* d_out, int out_size, void* d_ws, size_t ws_size,
                              hipStream_t stream){
  const float* x  = (const float*)d_in[0];
  const int* mask = (const int*)  d_in[1];
  const float* Wq = (const float*)d_in[2];
  const float* Wk = (const float*)d_in[3];
  const float* Wv = (const float*)d_in[4];
  const float* Wo = (const float*)d_in[5];
  float* out = (float*)d_out;

  char* ws = (char*)d_ws;                                  // total 48 MiB
  unsigned short* x_bf  = (unsigned short*)(ws);           //  8 MiB  [4096][1024]
  unsigned short* wt    = (unsigned short*)(ws + 8388608); //  6 MiB  [3072][1024] (QKV B^T)
  unsigned short* wo_bf = (unsigned short*)(ws + 14680064);//  2 MiB  [1024][1024]
  unsigned short* qb    = (unsigned short*)(ws + 16777216);//  8 MiB  [b][h][s][e] (pre-scaled)
  unsigned short* kb    = (unsigned short*)(ws + 25165824);//  8 MiB  compacted [b][h][j][e]
  unsigned short* vtb   = (unsigned short*)(ws + 33554432);//  8 MiB  compacted [b][h][e][j]
  unsigned short* ctx   = (unsigned short*)(ws + 41943040);//  8 MiB  [b][s][h*64+e]
  // pidx lives prep->gemm0 only; ctx region is dead until flash -> alias is safe
  int*            pidx  = (int*)(ws + 41943040);           // 16 KB   [b][s] compacted pos

  prep<<<PREP_ZB + PREP_CVT + PREP_TR + 2, 256, 0, stream>>>(
      x, Wo, Wq, Wk, Wv, mask, x_bf, wo_bf, wt, kb, pidx);
  gemm_bt<128><<<dim3(24, 32), 256, 0, stream>>>(x_bf, wt, qb, kb, vtb, nullptr, pidx, 4096, 3072, 1024, 0);
  flash_attn<<<512, 512, 0, stream>>>(qb, kb, vtb, mask, ctx);
  gemm_bt<64><<<dim3(8, 64), 256, 0, stream>>>(ctx, wo_bf, nullptr, nullptr, nullptr, out, pidx, 4096, 1024, 1024, 2);
}

// Round 16
// 172.067 us; speedup vs baseline: 1.0532x; 1.0038x over previous
//
#include <hip/hip_runtime.h>
#include <hip/hip_bf16.h>

typedef __attribute__((ext_vector_type(8))) short sh8;     // 8 bf16 (4 VGPRs)
typedef __attribute__((ext_vector_type(4))) float f32x4;   // MFMA C/D

#define LDC 136   // gemm epilogue C-tile stride in shorts
#define QSCALE 0.18033688f   // 0.125 * log2(e): folded into q at GEMM epilogue
#define KMBF16 0xF14Au       // bf16(-1e30): exp2(score-1e30) == 0 exactly

#define EXP2F(x) __builtin_amdgcn_exp2f(x)   // v_exp_f32 (base-2), no libm wrapper

// async global->LDS DMA, 16B/lane; LDS dest = wave-uniform base + lane*16 (m104/m108)
__device__ __forceinline__ void glds16(const unsigned short* g, unsigned short* l){
  __builtin_amdgcn_global_load_lds(
      (const __attribute__((address_space(1))) unsigned int*)g,
      (__attribute__((address_space(3))) unsigned int*)l, 16, 0, 0);
}

__device__ __forceinline__ unsigned short f2bf(float f){
  union { float f; unsigned u; } c; c.f = f;
  unsigned u = c.u;
  u += 0x7fffu + ((u >> 16) & 1u);   // RNE
  return (unsigned short)(u >> 16);
}

__device__ __forceinline__ unsigned long long pack4bf(float a, float b, float c, float d){
  __hip_bfloat162 lo = __float22bfloat162_rn(make_float2(a, b));  // v_cvt_pk_bf16_f32
  __hip_bfloat162 hi = __float22bfloat162_rn(make_float2(c, d));
  union { unsigned u[2]; unsigned long long ull; } pk;
  pk.u[0] = *(unsigned*)&lo; pk.u[1] = *(unsigned*)&hi;
  return pk.ull;
}

// ---------------- fused prep: zero kb/vtb + mask scan + fp32->bf16 cvt + W transpose ----------------
// R14: 7 dispatches -> 4 (~9us gap each). R15/R16: scan emits the REVERSE map
// gidx[b][j]=s (zero tail) + nv[b], enabling M-compacted KV-GEMM.
#define PREP_ZB   4096
#define PREP_CVT  5120
#define PREP_TR   768
__global__ __launch_bounds__(256) void prep(const float* __restrict__ x,
                                            const float* __restrict__ Wo,
                                            const float* __restrict__ Wq,
                                            const float* __restrict__ Wk,
                                            const float* __restrict__ Wv,
                                            const int* __restrict__ mask,
                                            unsigned short* __restrict__ x_bf,
                                            unsigned short* __restrict__ wo_bf,
                                            unsigned short* __restrict__ wt,
                                            unsigned short* __restrict__ kb_zero,  // kb base (16MiB contiguous with vtb)
                                            int* __restrict__ gidx,
                                            int* __restrict__ nv){
  __shared__ float tile[64][65];
  const int blk = blockIdx.x;
  const int t = threadIdx.x;

  if (blk < PREP_ZB){
    // zero kb+vtb (16 MiB): pads stay 0; gemm0 writes only valid positions
    ((uint4*)kb_zero)[(size_t)blk*256 + t] = make_uint4(0,0,0,0);
    return;
  }
  if (blk < PREP_ZB + PREP_CVT){
    int i = (blk - PREP_ZB)*256 + t;
    const float* s; unsigned short* d;
    if (i < 1048576){ s = x; d = x_bf; }
    else { s = Wo; d = wo_bf; i -= 1048576; }
    float4 v = ((const float4*)s)[i];
    ushort4 o;
    o.x = f2bf(v.x); o.y = f2bf(v.y); o.z = f2bf(v.z); o.w = f2bf(v.w);
    ((ushort4*)d)[i] = o;
    return;
  }
  if (blk < PREP_ZB + PREP_CVT + PREP_TR){
    int idx = blk - (PREP_ZB + PREP_CVT);    // 0..767 = 3 * 16(h) * 16(dt)
    int jm = idx >> 8;
    int rest = idx & 255;
    int h = rest >> 4, dt = rest & 15;
    const float* src = (jm==0 ? Wq : (jm==1 ? Wk : Wv)) + (size_t)h*65536;  // [D][64] slab
    {
      int r = t >> 2, c0 = (t & 3)*16;
      for (int i=0;i<4;++i){
        float4 v = *(const float4*)&src[(size_t)(dt*64 + r)*64 + c0 + i*4];
        tile[r][c0+i*4+0]=v.x; tile[r][c0+i*4+1]=v.y; tile[r][c0+i*4+2]=v.z; tile[r][c0+i*4+3]=v.w;
      }
    }
    __syncthreads();
    {
      int e = t >> 2, r0 = (t & 3)*16;
      int j = jm*1024 + h*64 + e;
      __align__(16) unsigned short buf[16];
      for (int i=0;i<16;++i) buf[i] = f2bf(tile[r0+i][e]);
      *(uint4*)&wt[(size_t)j*1024 + dt*64 + r0    ] = *(uint4*)&buf[0];
      *(uint4*)&wt[(size_t)j*1024 + dt*64 + r0 + 8] = *(uint4*)&buf[8];
    }
    return;
  }
  {
    // mask scan (R11-verified ballot-prefix) -> gidx reverse map + nv
    int b = blk - (PREP_ZB + PREP_CVT + PREP_TR);
    if (t >= 64) return;
    int lane = t;
    int m[32];
    #pragma unroll
    for (int c = 0; c < 32; ++c) m[c] = mask[b*2048 + c*64 + lane];   // independent loads
    #pragma unroll
    for (int c = 0; c < 32; ++c) gidx[b*2048 + c*64 + lane] = 0;      // zero tail default
    int base = 0;
    #pragma unroll
    for (int c = 0; c < 32; ++c){
      unsigned long long bal = __ballot(m[c] != 0);
      int pos = base + (int)__popcll(bal & ((1ULL << lane) - 1ULL));
      if (m[c]) gidx[b*2048 + pos] = c*64 + lane;                     // valid pos -> s
      base += (int)__popcll(bal);
    }
    if (lane == 0) nv[b] = base;
  }
}

// ---------------- GEMM C[M,N] = A[M,K] * Bt[N,K]^T, bf16 in / fp32 acc ----------------
// R13: BK=64 proven swizzle + counted-vmcnt deep pipeline, 2 buffers. Per step:
//   wait vmcnt(LOADS) [next tile in flight] -> s_barrier -> ds_read ALL frags
//   -> lgkmcnt(0) -> s_barrier (LDS-only) -> stage(ks+2) into cb -> MFMAs.
// R15/R16: KV-region blocks (mode 0, n0>=1024) run in COMPACTED M space: early-return
// if j0 >= nv[b] (~1/3 of blocks exit), A rows gathered via gidx (glds16 global src is
// per-lane), K/V epilogues dense. R16 FIX: gathered row is b*2048 + gidx[...] (R15
// omitted the batch base -> batch 1 read batch 0's x; absmax 0.091).
// Same-XCD group swizzle kept. mode 0: fused QKV. mode 2: Cf fp32.
template<int BM>
__global__ __launch_bounds__(256) void gemm_bt(const unsigned short* __restrict__ A,
                                               const unsigned short* __restrict__ Bt,
                                               unsigned short* __restrict__ Cq,
                                               unsigned short* __restrict__ Ck,
                                               unsigned short* __restrict__ Cv,
                                               float* __restrict__ Cf,
                                               const int* __restrict__ gidx,
                                               const int* __restrict__ nv,
                                               int M, int N, int K, int mode){
  constexpr int MI = BM/32;                 // acc rows per wave (4 or 2)
  constexpr int ABUF = BM*64;               // shorts per A buffer (BK=64)
  constexpr int BBUF = 128*64;              // shorts per B buffer
  constexpr int BUFN = ABUF + BBUF;
  constexpr int TOTN = 2*BUFN;
  constexpr int SMEMN = (TOTN > 17408) ? TOTN : 17408;  // >= Ct(17408)
  __shared__ __align__(16) unsigned short smem[SMEMN];
  const int t = threadIdx.x;
  const int w = t >> 6, lane = t & 63, l15 = lane & 15, quad = lane >> 4;

  // block swizzle: 8 m-blocks share one B-column tile AND one XCD
  int lin = blockIdx.y * gridDim.x + blockIdx.x;
  int gn = gridDim.x;
  int per = 8 * gn;
  int gid = lin / per, rem = lin % per;
  int j = rem / gn, nc = rem % gn;
  const int m0 = (gid*8 + j) * BM;
  const int n0 = nc * 128;

  const int wm = (w >> 1)*(BM/2), wn = (w & 1)*64;
  const int lr8 = lane >> 3;              // row within the wave's 8-row staging group
  const int gc8 = (lane & 7) ^ lr8;       // swizzled global chunk this lane fetches
  const int h7 = l15 & 7;

  // R15/R16: compacted-M for the KV region of mode 0
  const bool kvreg = (mode == 0) && (n0 >= 1024);
  const int b_ = m0 >> 11, j0_ = m0 & 2047;
  int nvb = 0;
  int arow[MI];
  if (kvreg){
    nvb = nv[b_];
    if (j0_ >= nvb) return;               // whole block's rows are pad -> kb/vtb stay 0
    #pragma unroll
    for (int p = 0; p < MI; ++p)
      arow[p] = b_*2048 + gidx[b_*2048 + j0_ + p*32 + w*8 + lr8];   // R16: + batch base
  }
  f32x4 acc[MI][4] = {};

  // stage one BK=64 K-slice starting at k0 into buffer bb (async, no wait)
  auto stage = [&](int k0, int bb){
    unsigned short* as = smem + bb*BUFN;
    unsigned short* bs = as + ABUF;
    for (int p = 0; p < BM/32; ++p){
      int rbase = p*32 + w*8;             // wave-uniform
      const unsigned short* src = kvreg
        ? &A[(size_t)arow[p]*K + k0 + gc8*8]
        : &A[(size_t)(m0 + rbase + lr8)*K + k0 + gc8*8];
      glds16(src, &as[rbase*64]);
    }
    for (int p = 0; p < 4; ++p){
      int rbase = p*32 + w*8;
      glds16(&Bt[(size_t)(n0 + rbase + lr8)*K + k0 + gc8*8], &bs[rbase*64]);
    }
  };

  const int NS = K >> 6;                    // 16 steps at K=1024
  stage(0, 0);
  stage(64, 1);
  for (int ks = 0; ks < NS; ++ks){
    const int cb = ks & 1;
    // counted wait: tile ks's loads done, tile ks+1's stay in flight (T4)
    if (ks == NS - 1){
      asm volatile("s_waitcnt vmcnt(0)" ::: "memory");
    } else {
      if constexpr (BM == 128) asm volatile("s_waitcnt vmcnt(8)" ::: "memory");
      else                     asm volatile("s_waitcnt vmcnt(6)" ::: "memory");
    }
    __builtin_amdgcn_s_barrier();           // buffer cb complete for all waves
    __builtin_amdgcn_sched_barrier(0);

    const unsigned short* as = smem + cb*BUFN;
    const unsigned short* bs = as + ABUF;
    sh8 aF[2][MI], bF[2][4];
    #pragma unroll
    for (int kk = 0; kk < 2; ++kk){
      const int cs = (((kk<<2) + quad) ^ h7) * 8;
      for (int i = 0; i < MI; ++i)
        aF[kk][i] = *(const sh8*)&as[(wm + i*16 + l15)*64 + cs];
      for (int i = 0; i < 4; ++i)
        bF[kk][i] = *(const sh8*)&bs[(wn + i*16 + l15)*64 + cs];
    }
    asm volatile("s_waitcnt lgkmcnt(0)" ::: "memory");
    __builtin_amdgcn_sched_barrier(0);
    __builtin_amdgcn_s_barrier();           // all waves' reads of cb done
    __builtin_amdgcn_sched_barrier(0);
    if (ks + 2 < NS) stage((ks+2)*64, cb);  // overwrite cb; lands ~2 steps later

    #pragma unroll
    for (int kk = 0; kk < 2; ++kk)
      for (int mi = 0; mi < MI; ++mi)
        for (int ni = 0; ni < 4; ++ni)
          acc[mi][ni] = __builtin_amdgcn_mfma_f32_16x16x32_bf16(aF[kk][mi], bF[kk][ni], acc[mi][ni], 0, 0, 0);
  }

  // C/D layout: col = lane&15, row = quad*4 + r (m89/m91-verified)
  if (mode == 2){
    for (int mi = 0; mi < MI; ++mi){
      int rowb = m0 + wm + mi*16 + quad*4;
      for (int ni = 0; ni < 4; ++ni){
        int col = n0 + wn + ni*16 + l15;
        for (int r = 0; r < 4; ++r)
          Cf[(size_t)(rowb + r)*N + col] = acc[mi][ni][r];
      }
    }
    return;
  }

  if constexpr (BM == 128){
    // mode 0: LDS round-trip epilogue. Ct = 128x136 shorts aliases smem (bufs dead now).
    __syncthreads();
    unsigned short* Ct = smem;
    const bool isv = (n0 >= 2048);
    const bool isq = (n0 < 1024);
    const float cscale = isq ? QSCALE : 1.0f;   // fold softmax scale into q
    for (int mi = 0; mi < 4; ++mi){
      for (int ni = 0; ni < 4; ++ni){
        for (int r = 0; r < 4; ++r){
          int lr = wm + mi*16 + quad*4 + r;   // local m index
          int lc = wn + ni*16 + l15;          // local n (col) index
          unsigned short bv = f2bf(acc[mi][ni][r] * cscale);
          if (isv) Ct[lc*LDC + lr] = bv;      // transposed for V
          else     Ct[lr*LDC + lc] = bv;
        }
      }
    }
    __syncthreads();

    const int hbase = (n0 & 1023) >> 6;
    if (!isv){
      unsigned short* dst = isq ? Cq : Ck;
      for (int i = 0; i < 8; ++i){
        int s  = i*16 + (t >> 4);
        int hh = (t >> 3) & 1;
        int c  = t & 7;
        uint4 val = *(const uint4*)&Ct[s*LDC + hh*64 + c*8];
        int h = hbase + hh;
        int row = j0_ + s;                    // Q: original s; K: compacted j (dense)
        if (!isq && row >= nvb) continue;     // K tail rows are pad
        *(uint4*)&dst[((size_t)(b_*16 + h)*2048 + row)*64 + c*8] = val;
      }
    } else {
      for (int i = 0; i < 8; ++i){
        int ecol = i*16 + (t >> 4);
        int s0   = (t & 15)*8;
        int hh = ecol >> 6, e = ecol & 63;
        int h = hbase + hh;
        unsigned short* dr = &Cv[((size_t)(b_*16 + h)*64 + e)*2048];
        union { uint4 v; unsigned short us[8]; } val;
        val.v = *(const uint4*)&Ct[ecol*LDC + s0];   // vectorized LDS read
        int c0 = j0_ + s0;                    // dense compacted V cols
        if (c0 + 7 < nvb){
          *(uint4*)&dr[c0] = val.v;           // fully valid -> 16B store
        } else {
          #pragma unroll
          for (int jj = 0; jj < 8; ++jj)
            if (c0 + jj < nvb) dr[c0 + jj] = val.us[jj];
        }
      }
    }
  }
}

// ---------------- flash attention over COMPACTED keys: 8 waves x 1 q-strip, dbuf ----------------
// R10/R11 verified: keys compacted to nv -> ntiles ~ 16-17 instead of 32 (flash < 46us).
// nv computed in-kernel from mask; pad-kill table (j<nv) kills the zero-padded tail;
// query mask applied at epilogue from mask[].
__global__ __launch_bounds__(512) void flash_attn(const unsigned short* __restrict__ q,
                                                  const unsigned short* __restrict__ k,
                                                  const unsigned short* __restrict__ vt,
                                                  const int* __restrict__ mask,
                                                  unsigned short* __restrict__ ctx){
  __shared__ __align__(16) unsigned short Ks[2][4096];   // [buf][64 key][64 e] xor-swizzled
  __shared__ __align__(16) unsigned short Vs[2][4096];   // [buf][64 e][64 key] xor-swizzled
  __shared__ __align__(16) unsigned short Ps[8][1024];   // [wave][16 qrow][64 key] xor-swz
  __shared__ __align__(16) unsigned short kmb[2048];     // bf16 adds: j<nv ? 0 : -1e30
  __shared__ int s_nv;

  const int idx = blockIdx.x;
  const int xcd = idx & 7, sub = idx >> 3;
  const int bh = xcd*4 + (sub & 3);           // 4 (b,h) per XCD -> K/V L2-resident
  const int qt = sub >> 2;                    // 0..15
  const int b = bh >> 4, h = bh & 15;
  const int t = threadIdx.x;
  const int w = t >> 6, lane = t & 63, l15 = lane & 15, quad = lane >> 4;
  const size_t base = (size_t)bh * 2048 * 64;

  // Q B-fragments for this wave's strip straight from global (q pre-scaled by QSCALE)
  const unsigned short* qp0 = q + base + (size_t)(qt*128 + w*16 + l15)*64;
  sh8 qf[2];
  qf[0] = *(const sh8*)(qp0 +      quad*8);
  qf[1] = *(const sh8*)(qp0 + 32 + quad*8);

  // count valid keys (nv) from mask: 512 threads x 4 ints, wave-reduce + one atomic/wave
  if (t == 0) s_nv = 0;
  int4 mv = ((const int4*)(mask + b*2048))[t];
  __syncthreads();
  {
    int c = (mv.x != 0) + (mv.y != 0) + (mv.z != 0) + (mv.w != 0);
    c += __shfl_down(c, 32); c += __shfl_down(c, 16); c += __shfl_down(c, 8);
    c += __shfl_down(c, 4);  c += __shfl_down(c, 2);  c += __shfl_down(c, 1);
    if (lane == 0) atomicAdd(&s_nv, c);
  }
  __syncthreads();
  const int nv = s_nv;
  const int ntiles = (nv + 63) >> 6;

  { // build pad-kill table: entry j = (j < nv) ? 0 : bf16(-1e30)
    __align__(8) unsigned short tmp[4];
    #pragma unroll
    for (int i = 0; i < 4; ++i) tmp[i] = (t*4 + i < nv) ? 0 : (unsigned short)KMBF16;
    *(unsigned long long*)&kmb[t*4] = *(unsigned long long*)tmp;
  }

  const int lr8 = lane >> 3;              // staging row within 8-row group
  const int gc8 = (lane & 7) ^ lr8;       // swizzled global source chunk
  const int h7 = l15 & 7;
  const int cs0 = ((quad    ) ^ h7) * 8;  // kk=0 swizzled read chunk (K/V tiles)
  const int cs1 = ((quad + 4) ^ h7) * 8;  // kk=1
  // Ps swizzle: write chunk8 (mt*2+(quad>>1))^h7 (+ (quad&1)*4), read chunk8 (kk*4+quad)^h7
  const int pw_off = (quad & 1)*4;
  const int pr0 = ((0*4 + quad) ^ h7) * 8;
  const int pr1 = ((1*4 + quad) ^ h7) * 8;

  // stage compacted K/V tile kt into buffer bb: wave w covers rows w*8..w*8+7 (1 glds each)
  auto stageKV = [&](int kt, int bb){
    int r0 = w*8;                         // wave-uniform LDS base row
    glds16(&k [base + (size_t)(kt*64 + r0 + lr8)*64 + gc8*8], &Ks[bb][r0*64]);
    glds16(&vt[base + (size_t)(r0 + lr8)*2048 + kt*64 + gc8*8], &Vs[bb][r0*64]);
  };

  float la[4] = {};
  f32x4 O[4] = {};   // O^T[et]: row=quad*4+r=e, col=l15=qrow

  if (ntiles > 0) stageKV(0, 0);
  for (int kt = 0; kt < ntiles; ++kt){
    const int bb = kt & 1;
    __syncthreads();                      // buf bb staged; prev compute done
    if (kt + 1 < ntiles) stageKV(kt + 1, bb ^ 1);   // async into other buffer

    // S^T = K·Q^T + km (pad-kill folded into the MFMA C-init)
    for (int mt = 0; mt < 4; ++mt){
      sh8 a0 = *(const sh8*)&Ks[bb][(mt*16 + l15)*64 + cs0];
      sh8 a1 = *(const sh8*)&Ks[bb][(mt*16 + l15)*64 + cs1];
      unsigned long long kq = *(const unsigned long long*)&kmb[kt*64 + mt*16 + quad*4];
      unsigned d0 = (unsigned)kq, d1 = (unsigned)(kq >> 32);
      f32x4 a;
      a[0] = __uint_as_float(d0 << 16);
      a[1] = __uint_as_float(d0 & 0xFFFF0000u);
      a[2] = __uint_as_float(d1 << 16);
      a[3] = __uint_as_float(d1 & 0xFFFF0000u);
      const int pwc = (((mt*2 + (quad>>1)) ^ h7) * 8) + pw_off;
      a = __builtin_amdgcn_mfma_f32_16x16x32_bf16(a0, qf[0], a, 0, 0, 0);
      a = __builtin_amdgcn_mfma_f32_16x16x32_bf16(a1, qf[1], a, 0, 0, 0);
      float e0 = EXP2F(a[0]); la[0] += e0;
      float e1 = EXP2F(a[1]); la[1] += e1;
      float e2 = EXP2F(a[2]); la[2] += e2;
      float e3 = EXP2F(a[3]); la[3] += e3;
      *(unsigned long long*)&Ps[w][l15*64 + pwc] = pack4bf(e0, e1, e2, e3);
    }

    // O^T += V^T · P (Ps per-wave: no barrier needed)
    sh8 pf0 = *(const sh8*)&Ps[w][l15*64 + pr0];
    sh8 pf1 = *(const sh8*)&Ps[w][l15*64 + pr1];
    for (int et = 0; et < 4; ++et){
      sh8 vf0 = *(const sh8*)&Vs[bb][(et*16 + l15)*64 + cs0];
      O[et] = __builtin_amdgcn_mfma_f32_16x16x32_bf16(vf0, pf0, O[et], 0, 0, 0);
    }
    for (int et = 0; et < 4; ++et){
      sh8 vf1 = *(const sh8*)&Vs[bb][(et*16 + l15)*64 + cs1];
      O[et] = __builtin_amdgcn_mfma_f32_16x16x32_bf16(vf1, pf1, O[et], 0, 0, 0);
    }
  }

  // epilogue: final l reduction, /l, query-mask zeroing (from original mask)
  {
    float l_i = (la[0] + la[1]) + (la[2] + la[3]);
    l_i += __shfl_xor(l_i, 16);
    l_i += __shfl_xor(l_i, 32);
    int srow = qt*128 + w*16 + l15;
    bool qm = (mask[b*2048 + srow] != 0);
    float inv = (qm && l_i > 0.f) ? 1.f/l_i : 0.f;
    unsigned short* crow = ctx + (((size_t)b*2048 + srow)*16 + h)*64;
    for (int et = 0; et < 4; ++et)
      *(unsigned long long*)&crow[et*16 + quad*4] =
        pack4bf(O[et][0]*inv, O[et][1]*inv, O[et][2]*inv, O[et][3]*inv);
  }
}

extern "C" void kernel_launch(void* const* d_in, const int* in_sizes, int n_in,
                              void* d_out, int out_size, void* d_ws, size_t ws_size,
                              hipStream_t stream){
  const float* x  = (const float*)d_in[0];
  const int* mask = (const int*)  d_in[1];
  const float* Wq = (const float*)d_in[2];
  const float* Wk = (const float*)d_in[3];
  const float* Wv = (const float*)d_in[4];
  const float* Wo = (const float*)d_in[5];
  float* out = (float*)d_out;

  char* ws = (char*)d_ws;                                  // total 48 MiB
  unsigned short* x_bf  = (unsigned short*)(ws);           //  8 MiB  [4096][1024]
  unsigned short* wt    = (unsigned short*)(ws + 8388608); //  6 MiB  [3072][1024] (QKV B^T)
  unsigned short* wo_bf = (unsigned short*)(ws + 14680064);//  2 MiB  [1024][1024]
  unsigned short* qb    = (unsigned short*)(ws + 16777216);//  8 MiB  [b][h][s][e] (pre-scaled)
  unsigned short* kb    = (unsigned short*)(ws + 25165824);//  8 MiB  compacted [b][h][j][e]
  unsigned short* vtb   = (unsigned short*)(ws + 33554432);//  8 MiB  compacted [b][h][e][j]
  unsigned short* ctx   = (unsigned short*)(ws + 41943040);//  8 MiB  [b][s][h*64+e]
  // gidx/nv live prep->gemm0 only; ctx region is dead until flash -> alias is safe
  int*            gidx  = (int*)(ws + 41943040);           // 16 KB   [b][j] -> s reverse map
  int*            nvbuf = (int*)(ws + 41943040 + 16384);   // 8 B     valid count per b

  prep<<<PREP_ZB + PREP_CVT + PREP_TR + 2, 256, 0, stream>>>(
      x, Wo, Wq, Wk, Wv, mask, x_bf, wo_bf, wt, kb, gidx, nvbuf);
  gemm_bt<128><<<dim3(24, 32), 256, 0, stream>>>(x_bf, wt, qb, kb, vtb, nullptr, gidx, nvbuf, 4096, 3072, 1024, 0);
  flash_attn<<<512, 512, 0, stream>>>(qb, kb, vtb, mask, ctx);
  gemm_bt<64><<<dim3(8, 64), 256, 0, stream>>>(ctx, wo_bf, nullptr, nullptr, nullptr, out, nullptr, nullptr, 4096, 1024, 1024, 2);
}

// Round 17
// 171.169 us; speedup vs baseline: 1.0588x; 1.0052x over previous
//
#include <hip/hip_runtime.h>
#include <hip/hip_bf16.h>

typedef __attribute__((ext_vector_type(8))) short sh8;     // 8 bf16 (4 VGPRs)
typedef __attribute__((ext_vector_type(4))) float f32x4;   // MFMA C/D

#define LDC 136   // gemm epilogue C-tile stride in shorts
#define QSCALE 0.18033688f   // 0.125 * log2(e): folded into q at GEMM epilogue
#define KMBF16 0xF14Au       // bf16(-1e30): exp2(score-1e30) == 0 exactly

#define EXP2F(x) __builtin_amdgcn_exp2f(x)   // v_exp_f32 (base-2), no libm wrapper

// async global->LDS DMA, 16B/lane; LDS dest = wave-uniform base + lane*16 (m104/m108)
__device__ __forceinline__ void glds16(const unsigned short* g, unsigned short* l){
  __builtin_amdgcn_global_load_lds(
      (const __attribute__((address_space(1))) unsigned int*)g,
      (__attribute__((address_space(3))) unsigned int*)l, 16, 0, 0);
}

__device__ __forceinline__ unsigned short f2bf(float f){
  union { float f; unsigned u; } c; c.f = f;
  unsigned u = c.u;
  u += 0x7fffu + ((u >> 16) & 1u);   // RNE
  return (unsigned short)(u >> 16);
}

__device__ __forceinline__ unsigned long long pack4bf(float a, float b, float c, float d){
  __hip_bfloat162 lo = __float22bfloat162_rn(make_float2(a, b));  // v_cvt_pk_bf16_f32
  __hip_bfloat162 hi = __float22bfloat162_rn(make_float2(c, d));
  union { unsigned u[2]; unsigned long long ull; } pk;
  pk.u[0] = *(unsigned*)&lo; pk.u[1] = *(unsigned*)&hi;
  return pk.ull;
}

// ---------------- fused prep: zero kb/vtb + mask scan + fp32->bf16 cvt + W transpose ----------------
// R14: 7 dispatches -> 4 (~9us gap each). R17: back to FORWARD map pidx[s] (R15/R16's
// M-compacted gather regressed gemm0 50.6 vs 44.4: load imbalance + scattered-row
// staging latency; reverted).
#define PREP_ZB   4096
#define PREP_CVT  5120
#define PREP_TR   768
__global__ __launch_bounds__(256) void prep(const float* __restrict__ x,
                                            const float* __restrict__ Wo,
                                            const float* __restrict__ Wq,
                                            const float* __restrict__ Wk,
                                            const float* __restrict__ Wv,
                                            const int* __restrict__ mask,
                                            unsigned short* __restrict__ x_bf,
                                            unsigned short* __restrict__ wo_bf,
                                            unsigned short* __restrict__ wt,
                                            unsigned short* __restrict__ kb_zero,  // kb base (16MiB contiguous with vtb)
                                            int* __restrict__ pidx){
  __shared__ float tile[64][65];
  const int blk = blockIdx.x;
  const int t = threadIdx.x;

  if (blk < PREP_ZB){
    // zero kb+vtb (16 MiB): pads stay 0; gemm0 writes only valid positions
    ((uint4*)kb_zero)[(size_t)blk*256 + t] = make_uint4(0,0,0,0);
    return;
  }
  if (blk < PREP_ZB + PREP_CVT){
    int i = (blk - PREP_ZB)*256 + t;
    const float* s; unsigned short* d;
    if (i < 1048576){ s = x; d = x_bf; }
    else { s = Wo; d = wo_bf; i -= 1048576; }
    float4 v = ((const float4*)s)[i];
    ushort4 o;
    o.x = f2bf(v.x); o.y = f2bf(v.y); o.z = f2bf(v.z); o.w = f2bf(v.w);
    ((ushort4*)d)[i] = o;
    return;
  }
  if (blk < PREP_ZB + PREP_CVT + PREP_TR){
    int idx = blk - (PREP_ZB + PREP_CVT);    // 0..767 = 3 * 16(h) * 16(dt)
    int jm = idx >> 8;
    int rest = idx & 255;
    int h = rest >> 4, dt = rest & 15;
    const float* src = (jm==0 ? Wq : (jm==1 ? Wk : Wv)) + (size_t)h*65536;  // [D][64] slab
    {
      int r = t >> 2, c0 = (t & 3)*16;
      for (int i=0;i<4;++i){
        float4 v = *(const float4*)&src[(size_t)(dt*64 + r)*64 + c0 + i*4];
        tile[r][c0+i*4+0]=v.x; tile[r][c0+i*4+1]=v.y; tile[r][c0+i*4+2]=v.z; tile[r][c0+i*4+3]=v.w;
      }
    }
    __syncthreads();
    {
      int e = t >> 2, r0 = (t & 3)*16;
      int j = jm*1024 + h*64 + e;
      __align__(16) unsigned short buf[16];
      for (int i=0;i<16;++i) buf[i] = f2bf(tile[r0+i][e]);
      *(uint4*)&wt[(size_t)j*1024 + dt*64 + r0    ] = *(uint4*)&buf[0];
      *(uint4*)&wt[(size_t)j*1024 + dt*64 + r0 + 8] = *(uint4*)&buf[8];
    }
    return;
  }
  {
    // mask scan (R11-verified ballot-prefix): pidx[s] = compacted pos or -1
    int b = blk - (PREP_ZB + PREP_CVT + PREP_TR);
    if (t >= 64) return;
    int lane = t;
    int m[32];
    #pragma unroll
    for (int c = 0; c < 32; ++c) m[c] = mask[b*2048 + c*64 + lane];   // independent loads
    int base = 0;
    #pragma unroll
    for (int c = 0; c < 32; ++c){
      unsigned long long bal = __ballot(m[c] != 0);
      int pos = base + (int)__popcll(bal & ((1ULL << lane) - 1ULL));
      pidx[b*2048 + c*64 + lane] = m[c] ? pos : -1;
      base += (int)__popcll(bal);
    }
  }
}

// ---------------- GEMM C[M,N] = A[M,K] * Bt[N,K]^T, bf16 in / fp32 acc ----------------
// R17: BK=32 + 3-buffer rotation + counted vmcnt (R12 skeleton, which passed refcheck:
// Occ 13->22) with a CORRECT conflict-free swizzle (R12's cost 3.48M conflict cycles).
// Derivation: reader (row=l15, quad) takes phys chunk pc=(quad+(l15>>1))&3 -> each
// chunk used 2x per bank-half = 2-way alias (free, m136). DMA writes linear (row=
// lane>>2, chunk=lane&3) so lane pre-loads global logical chunk g=((lane&3)-(lane>>3))&3
// (both-sides-or-neither, rule 21). LDS 48KB -> 3 blocks/CU.
// Per step: wait vmcnt(LOADS) [next tile in flight] -> s_barrier -> stage(ks+2) ->
// ds_read frags -> 16 MFMAs. Uniform M; K/V epilogue scatters via pidx (R14-proven).
// mode 0: N=3072 fused QKV. mode 2: N=1024 -> Cf fp32.
template<int BM>
__global__ __launch_bounds__(256) void gemm_bt(const unsigned short* __restrict__ A,
                                               const unsigned short* __restrict__ Bt,
                                               unsigned short* __restrict__ Cq,
                                               unsigned short* __restrict__ Ck,
                                               unsigned short* __restrict__ Cv,
                                               float* __restrict__ Cf,
                                               const int* __restrict__ pidx,
                                               int M, int N, int K, int mode){
  constexpr int MI = BM/32;                 // acc rows per wave (4 or 2)
  constexpr int ABUF = BM*32;               // shorts per A buffer (BK=32)
  constexpr int BBUF = 128*32;              // shorts per B buffer
  constexpr int BUFN = ABUF + BBUF;
  constexpr int TOTN = 3*BUFN;              // 3-buffer rotation (24576 shorts @BM=128)
  constexpr int SMEMN = (TOTN > 17664) ? TOTN : 17664;  // >= Ct(17408)+pS(128 ints)
  __shared__ __align__(16) unsigned short smem[SMEMN];
  const int t = threadIdx.x;
  const int w = t >> 6, lane = t & 63, l15 = lane & 15, quad = lane >> 4;

  // block swizzle: 8 m-blocks share one B-column tile AND one XCD
  int lin = blockIdx.y * gridDim.x + blockIdx.x;
  int gn = gridDim.x;
  int per = 8 * gn;
  int gid = lin / per, rem = lin % per;
  int j = rem / gn, nc = rem % gn;
  const int m0 = (gid*8 + j) * BM;
  const int n0 = nc * 128;

  const int wm = (w >> 1)*(BM/2), wn = (w & 1)*64;
  const int lr16 = lane >> 2;               // DMA row within 16-row group
  const int gq   = ((lane & 3) - (lane >> 3)) & 3;         // pre-swizzled global chunk
  const int cs   = ((quad + (l15 >> 1)) & 3) * 8;          // read phys chunk * 8 shorts
  f32x4 acc[MI][4] = {};

  // stage one BK=32 K-slice starting at k0 into buffer bb (async, no wait)
  auto stage = [&](int k0, int bb){
    unsigned short* as = smem + bb*BUFN;
    unsigned short* bs = as + ABUF;
    for (int p = 0; p < BM/64; ++p){
      int r0 = w*(BM/4) + p*16;             // wave-uniform
      glds16(&A [(size_t)(m0 + r0 + lr16)*K + k0 + gq*8], &as[r0*32]);
    }
    for (int p = 0; p < 2; ++p){
      int r0 = w*32 + p*16;
      glds16(&Bt[(size_t)(n0 + r0 + lr16)*K + k0 + gq*8], &bs[r0*32]);
    }
  };

  const int NS = K >> 5;                    // 32 steps at K=1024
  stage(0, 0);
  stage(32, 1);
  int cb = 0, sb = 2;                       // compute buf = ks%3, stage buf = (ks+2)%3
  for (int ks = 0; ks < NS; ++ks){
    // counted wait: tile ks's loads done, tile ks+1's stay in flight (T4)
    if (ks == NS - 1){
      asm volatile("s_waitcnt vmcnt(0)" ::: "memory");
    } else {
      if constexpr (BM == 128) asm volatile("s_waitcnt vmcnt(4)" ::: "memory");
      else                     asm volatile("s_waitcnt vmcnt(3)" ::: "memory");
    }
    __builtin_amdgcn_s_barrier();           // all waves' tile-ks loads done -> buffer ready
    __builtin_amdgcn_sched_barrier(0);      // pin: no ds_read hoisted above the barrier
    if (ks + 2 < NS) stage((ks+2)*32, sb);  // safe: all waves past compute(ks-1)

    const unsigned short* as = smem + cb*BUFN;
    const unsigned short* bs = as + ABUF;
    sh8 aF[MI], bF[4];
    for (int i = 0; i < MI; ++i)
      aF[i] = *(const sh8*)&as[(wm + i*16 + l15)*32 + cs];
    for (int i = 0; i < 4; ++i)
      bF[i] = *(const sh8*)&bs[(wn + i*16 + l15)*32 + cs];
    for (int mi = 0; mi < MI; ++mi)
      for (int ni = 0; ni < 4; ++ni)
        acc[mi][ni] = __builtin_amdgcn_mfma_f32_16x16x32_bf16(aF[mi], bF[ni], acc[mi][ni], 0, 0, 0);

    cb = (cb == 2) ? 0 : cb + 1;
    sb = (sb == 2) ? 0 : sb + 1;
  }

  // C/D layout: col = lane&15, row = quad*4 + r (m89/m91-verified)
  if (mode == 2){
    for (int mi = 0; mi < MI; ++mi){
      int rowb = m0 + wm + mi*16 + quad*4;
      for (int ni = 0; ni < 4; ++ni){
        int col = n0 + wn + ni*16 + l15;
        for (int r = 0; r < 4; ++r)
          Cf[(size_t)(rowb + r)*N + col] = acc[mi][ni][r];
      }
    }
    return;
  }

  if constexpr (BM == 128){
    // mode 0: LDS round-trip epilogue. Ct = 128x136 shorts aliases smem (bufs dead now).
    __syncthreads();
    unsigned short* Ct = smem;
    int* pS = (int*)(smem + 17408);       // pidx slice for this block's 128 s-rows
    const bool isv = (n0 >= 2048);
    const float cscale = (n0 < 1024) ? QSCALE : 1.0f;   // fold softmax scale into q
    const int b = m0 >> 11, sbase = m0 & 2047;
    for (int mi = 0; mi < 4; ++mi){
      for (int ni = 0; ni < 4; ++ni){
        for (int r = 0; r < 4; ++r){
          int lr = wm + mi*16 + quad*4 + r;   // local m (s) index
          int lc = wn + ni*16 + l15;          // local n (col) index
          unsigned short bv = f2bf(acc[mi][ni][r] * cscale);
          if (isv) Ct[lc*LDC + lr] = bv;      // transposed for V
          else     Ct[lr*LDC + lc] = bv;
        }
      }
    }
    if (t < 128) pS[t] = pidx[b*2048 + sbase + t];
    __syncthreads();

    const int hbase = (n0 & 1023) >> 6;
    if (!isv){
      const bool isq = (n0 < 1024);
      unsigned short* dst = isq ? Cq : Ck;
      for (int i = 0; i < 8; ++i){
        int s  = i*16 + (t >> 4);
        int hh = (t >> 3) & 1;
        int c  = t & 7;
        uint4 val = *(const uint4*)&Ct[s*LDC + hh*64 + c*8];
        int h = hbase + hh;
        int row;
        if (isq) row = sbase + s;
        else { int p = pS[s]; if (p < 0) continue; row = p; }   // compacted K row
        *(uint4*)&dst[((size_t)(b*16 + h)*2048 + row)*64 + c*8] = val;
      }
    } else {
      for (int i = 0; i < 8; ++i){
        int ecol = i*16 + (t >> 4);
        int s0   = (t & 15)*8;
        int hh = ecol >> 6, e = ecol & 63;
        int h = hbase + hh;
        unsigned short* dr = &Cv[((size_t)(b*16 + h)*64 + e)*2048];
        union { uint4 v; unsigned short us[8]; } val;
        val.v = *(const uint4*)&Ct[ecol*LDC + s0];   // vectorized LDS read
        #pragma unroll
        for (int jj = 0; jj < 8; ++jj){
          int p = pS[s0 + jj];
          if (p >= 0) dr[p] = val.us[jj];            // compacted V col (2B scatter)
        }
      }
    }
  }
}

// ---------------- flash attention over COMPACTED keys: 8 waves x 1 q-strip, dbuf ----------------
// R10/R11 verified: keys compacted to nv -> ntiles ~ 16-17 instead of 32 (flash < 46us).
// nv computed in-kernel from mask; pad-kill table (j<nv) kills the zero-padded tail;
// query mask applied at epilogue from mask[].
__global__ __launch_bounds__(512) void flash_attn(const unsigned short* __restrict__ q,
                                                  const unsigned short* __restrict__ k,
                                                  const unsigned short* __restrict__ vt,
                                                  const int* __restrict__ mask,
                                                  unsigned short* __restrict__ ctx){
  __shared__ __align__(16) unsigned short Ks[2][4096];   // [buf][64 key][64 e] xor-swizzled
  __shared__ __align__(16) unsigned short Vs[2][4096];   // [buf][64 e][64 key] xor-swizzled
  __shared__ __align__(16) unsigned short Ps[8][1024];   // [wave][16 qrow][64 key] xor-swz
  __shared__ __align__(16) unsigned short kmb[2048];     // bf16 adds: j<nv ? 0 : -1e30
  __shared__ int s_nv;

  const int idx = blockIdx.x;
  const int xcd = idx & 7, sub = idx >> 3;
  const int bh = xcd*4 + (sub & 3);           // 4 (b,h) per XCD -> K/V L2-resident
  const int qt = sub >> 2;                    // 0..15
  const int b = bh >> 4, h = bh & 15;
  const int t = threadIdx.x;
  const int w = t >> 6, lane = t & 63, l15 = lane & 15, quad = lane >> 4;
  const size_t base = (size_t)bh * 2048 * 64;

  // Q B-fragments for this wave's strip straight from global (q pre-scaled by QSCALE)
  const unsigned short* qp0 = q + base + (size_t)(qt*128 + w*16 + l15)*64;
  sh8 qf[2];
  qf[0] = *(const sh8*)(qp0 +      quad*8);
  qf[1] = *(const sh8*)(qp0 + 32 + quad*8);

  // count valid keys (nv) from mask: 512 threads x 4 ints, wave-reduce + one atomic/wave
  if (t == 0) s_nv = 0;
  int4 mv = ((const int4*)(mask + b*2048))[t];
  __syncthreads();
  {
    int c = (mv.x != 0) + (mv.y != 0) + (mv.z != 0) + (mv.w != 0);
    c += __shfl_down(c, 32); c += __shfl_down(c, 16); c += __shfl_down(c, 8);
    c += __shfl_down(c, 4);  c += __shfl_down(c, 2);  c += __shfl_down(c, 1);
    if (lane == 0) atomicAdd(&s_nv, c);
  }
  __syncthreads();
  const int nv = s_nv;
  const int ntiles = (nv + 63) >> 6;

  { // build pad-kill table: entry j = (j < nv) ? 0 : bf16(-1e30)
    __align__(8) unsigned short tmp[4];
    #pragma unroll
    for (int i = 0; i < 4; ++i) tmp[i] = (t*4 + i < nv) ? 0 : (unsigned short)KMBF16;
    *(unsigned long long*)&kmb[t*4] = *(unsigned long long*)tmp;
  }

  const int lr8 = lane >> 3;              // staging row within 8-row group
  const int gc8 = (lane & 7) ^ lr8;       // swizzled global source chunk
  const int h7 = l15 & 7;
  const int cs0 = ((quad    ) ^ h7) * 8;  // kk=0 swizzled read chunk (K/V tiles)
  const int cs1 = ((quad + 4) ^ h7) * 8;  // kk=1
  // Ps swizzle: write chunk8 (mt*2+(quad>>1))^h7 (+ (quad&1)*4), read chunk8 (kk*4+quad)^h7
  const int pw_off = (quad & 1)*4;
  const int pr0 = ((0*4 + quad) ^ h7) * 8;
  const int pr1 = ((1*4 + quad) ^ h7) * 8;

  // stage compacted K/V tile kt into buffer bb: wave w covers rows w*8..w*8+7 (1 glds each)
  auto stageKV = [&](int kt, int bb){
    int r0 = w*8;                         // wave-uniform LDS base row
    glds16(&k [base + (size_t)(kt*64 + r0 + lr8)*64 + gc8*8], &Ks[bb][r0*64]);
    glds16(&vt[base + (size_t)(r0 + lr8)*2048 + kt*64 + gc8*8], &Vs[bb][r0*64]);
  };

  float la[4] = {};
  f32x4 O[4] = {};   // O^T[et]: row=quad*4+r=e, col=l15=qrow

  if (ntiles > 0) stageKV(0, 0);
  for (int kt = 0; kt < ntiles; ++kt){
    const int bb = kt & 1;
    __syncthreads();                      // buf bb staged; prev compute done
    if (kt + 1 < ntiles) stageKV(kt + 1, bb ^ 1);   // async into other buffer

    // S^T = K·Q^T + km (pad-kill folded into the MFMA C-init)
    for (int mt = 0; mt < 4; ++mt){
      sh8 a0 = *(const sh8*)&Ks[bb][(mt*16 + l15)*64 + cs0];
      sh8 a1 = *(const sh8*)&Ks[bb][(mt*16 + l15)*64 + cs1];
      unsigned long long kq = *(const unsigned long long*)&kmb[kt*64 + mt*16 + quad*4];
      unsigned d0 = (unsigned)kq, d1 = (unsigned)(kq >> 32);
      f32x4 a;
      a[0] = __uint_as_float(d0 << 16);
      a[1] = __uint_as_float(d0 & 0xFFFF0000u);
      a[2] = __uint_as_float(d1 << 16);
      a[3] = __uint_as_float(d1 & 0xFFFF0000u);
      const int pwc = (((mt*2 + (quad>>1)) ^ h7) * 8) + pw_off;
      a = __builtin_amdgcn_mfma_f32_16x16x32_bf16(a0, qf[0], a, 0, 0, 0);
      a = __builtin_amdgcn_mfma_f32_16x16x32_bf16(a1, qf[1], a, 0, 0, 0);
      float e0 = EXP2F(a[0]); la[0] += e0;
      float e1 = EXP2F(a[1]); la[1] += e1;
      float e2 = EXP2F(a[2]); la[2] += e2;
      float e3 = EXP2F(a[3]); la[3] += e3;
      *(unsigned long long*)&Ps[w][l15*64 + pwc] = pack4bf(e0, e1, e2, e3);
    }

    // O^T += V^T · P (Ps per-wave: no barrier needed)
    sh8 pf0 = *(const sh8*)&Ps[w][l15*64 + pr0];
    sh8 pf1 = *(const sh8*)&Ps[w][l15*64 + pr1];
    for (int et = 0; et < 4; ++et){
      sh8 vf0 = *(const sh8*)&Vs[bb][(et*16 + l15)*64 + cs0];
      O[et] = __builtin_amdgcn_mfma_f32_16x16x32_bf16(vf0, pf0, O[et], 0, 0, 0);
    }
    for (int et = 0; et < 4; ++et){
      sh8 vf1 = *(const sh8*)&Vs[bb][(et*16 + l15)*64 + cs1];
      O[et] = __builtin_amdgcn_mfma_f32_16x16x32_bf16(vf1, pf1, O[et], 0, 0, 0);
    }
  }

  // epilogue: final l reduction, /l, query-mask zeroing (from original mask)
  {
    float l_i = (la[0] + la[1]) + (la[2] + la[3]);
    l_i += __shfl_xor(l_i, 16);
    l_i += __shfl_xor(l_i, 32);
    int srow = qt*128 + w*16 + l15;
    bool qm = (mask[b*2048 + srow] != 0);
    float inv = (qm && l_i > 0.f) ? 1.f/l_i : 0.f;
    unsigned short* crow = ctx + (((size_t)b*2048 + srow)*16 + h)*64;
    for (int et = 0; et < 4; ++et)
      *(unsigned long long*)&crow[et*16 + quad*4] =
        pack4bf(O[et][0]*inv, O[et][1]*inv, O[et][2]*inv, O[et][3]*inv);
  }
}

extern "C" void kernel_launch(void* const* d_in, const int* in_sizes, int n_in,
                              void* d_out, int out_size, void* d_ws, size_t ws_size,
                              hipStream_t stream){
  const float* x  = (const float*)d_in[0];
  const int* mask = (const int*)  d_in[1];
  const float* Wq = (const float*)d_in[2];
  const float* Wk = (const float*)d_in[3];
  const float* Wv = (const float*)d_in[4];
  const float* Wo = (const float*)d_in[5];
  float* out = (float*)d_out;

  char* ws = (char*)d_ws;                                  // total 48 MiB
  unsigned short* x_bf  = (unsigned short*)(ws);           //  8 MiB  [4096][1024]
  unsigned short* wt    = (unsigned short*)(ws + 8388608); //  6 MiB  [3072][1024] (QKV B^T)
  unsigned short* wo_bf = (unsigned short*)(ws + 14680064);//  2 MiB  [1024][1024]
  unsigned short* qb    = (unsigned short*)(ws + 16777216);//  8 MiB  [b][h][s][e] (pre-scaled)
  unsigned short* kb    = (unsigned short*)(ws + 25165824);//  8 MiB  compacted [b][h][j][e]
  unsigned short* vtb   = (unsigned short*)(ws + 33554432);//  8 MiB  compacted [b][h][e][j]
  unsigned short* ctx   = (unsigned short*)(ws + 41943040);//  8 MiB  [b][s][h*64+e]
  // pidx lives prep->gemm0 only; ctx region is dead until flash -> alias is safe
  int*            pidx  = (int*)(ws + 41943040);           // 16 KB   [b][s] compacted pos

  prep<<<PREP_ZB + PREP_CVT + PREP_TR + 2, 256, 0, stream>>>(
      x, Wo, Wq, Wk, Wv, mask, x_bf, wo_bf, wt, kb, pidx);
  gemm_bt<128><<<dim3(24, 32), 256, 0, stream>>>(x_bf, wt, qb, kb, vtb, nullptr, pidx, 4096, 3072, 1024, 0);
  flash_attn<<<512, 512, 0, stream>>>(qb, kb, vtb, mask, ctx);
  gemm_bt<64><<<dim3(8, 64), 256, 0, stream>>>(ctx, wo_bf, nullptr, nullptr, nullptr, out, nullptr, 4096, 1024, 1024, 2);
}